// Round 1
// baseline (165305.969 us; speedup 1.0000x reference)
//
#include <hip/hip_runtime.h>
#include <hip/hip_bf16.h>
#include <math.h>

#define NN 40
#define BBATCH 32
#define DD 768
#define TT 820   // (N+1)*N/2

__device__ __forceinline__ int ftd(int b, int e) {
    int l = e - b;
    return TT - (NN - l + 2) * (NN - l + 1) / 2 + b;
}

#define MODE_CONTIG 0
#define MODE_IN 1
#define MODE_OUT 2

// Out[m][j] = act( sum_k A[m][k] * Wm[j][k] + bias[j] ),  Wm row-major (j-th row = KDIM weights)
// A rows gathered: MODE_CONTIG: Abase + m*KDIM ; MODE_IN/OUT: concat of two chart vectors.
template<int MODE, int KDIM, bool RELU, bool BIAS>
__global__ __launch_bounds__(256)
void gemm_w(const float* __restrict__ Abase,
            const float* __restrict__ iv, const float* __restrict__ ov,
            const float* __restrict__ Wm, const float* __restrict__ bias,
            float* __restrict__ Out, int M, int level, int g0, int Sps)
{
    __shared__ float As[16][68];
    __shared__ float Bs[16][68];
    __shared__ const float* Ap0[64];
    __shared__ const float* Ap1[64];
    const int tid = threadIdx.x;
    const int m0 = blockIdx.x * 64;
    const int j0 = blockIdx.y * 64;

    if (MODE != MODE_CONTIG) {
        if (tid < 64) {
            int r = m0 + tid; if (r >= M) r = M - 1;
            int p = r >> 5, bb = r & 31;
            int g = g0 + p / Sps, si = p % Sps;
            const float *lp, *rp;
            if (MODE == MODE_IN) {
                int s = si + 1;
                int lc = ftd(g, g + s), rc = ftd(g + s, g + level);
                lp = iv + (size_t)(lc * 32 + bb) * DD;
                rp = iv + (size_t)(rc * 32 + bb) * DD;
            } else {
                int pc, scl;
                if (si < g) { int c = si; pc = ftd(c, g + level); scl = ftd(c, g); }
                else { int c = si + level + 1; pc = ftd(g, c); scl = ftd(g + level, c); }
                lp = ov + (size_t)(pc * 32 + bb) * DD;
                rp = iv + (size_t)(scl * 32 + bb) * DD;
            }
            Ap0[tid] = lp; Ap1[tid] = rp;
        }
        __syncthreads();
    }

    float acc[4][4] = {};
    const int r0 = (tid >> 4) * 4;
    const int c0 = (tid & 15) * 4;
    const int lr = tid >> 2;           // 0..63 load row
    const int lk = (tid & 3) * 4;      // k offset within tile

    for (int k0 = 0; k0 < KDIM; k0 += 16) {
        float4 av;
        if (MODE == MODE_CONTIG) {
            int r = m0 + lr; if (r >= M) r = M - 1;
            av = *(const float4*)(Abase + (size_t)r * KDIM + k0 + lk);
        } else {
            int k = k0 + lk;
            const float* src = (k < DD) ? (Ap0[lr] + k) : (Ap1[lr] + (k - DD));
            av = *(const float4*)src;
        }
        As[lk+0][lr] = av.x; As[lk+1][lr] = av.y; As[lk+2][lr] = av.z; As[lk+3][lr] = av.w;
        float4 bv = *(const float4*)(Wm + (size_t)(j0 + lr) * KDIM + k0 + lk);
        Bs[lk+0][lr] = bv.x; Bs[lk+1][lr] = bv.y; Bs[lk+2][lr] = bv.z; Bs[lk+3][lr] = bv.w;
        __syncthreads();
        #pragma unroll
        for (int kk = 0; kk < 16; ++kk) {
            float4 a = *(const float4*)&As[kk][r0];
            float4 b = *(const float4*)&Bs[kk][c0];
            float ar[4] = {a.x, a.y, a.z, a.w};
            float br[4] = {b.x, b.y, b.z, b.w};
            #pragma unroll
            for (int i = 0; i < 4; ++i)
                #pragma unroll
                for (int j = 0; j < 4; ++j)
                    acc[i][j] += ar[i] * br[j];
        }
        __syncthreads();
    }
    #pragma unroll
    for (int i = 0; i < 4; ++i) {
        int r = m0 + r0 + i;
        if (r < M) {
            #pragma unroll
            for (int j = 0; j < 4; ++j) {
                float v = acc[i][j];
                if (BIAS) v += bias[j0 + c0 + j];
                if (RELU) v = fmaxf(v, 0.f);
                Out[(size_t)r * DD + j0 + c0 + j] = v;
            }
        }
    }
}

// Per output cell: out[bb][j] = sum_s w[s,bb] * relu( sum_k h1[(gl*S+s)*32+bb][k]*W2[j][k] + b2[j] )
__global__ __launch_bounds__(256)
void gemm2_w(const float* __restrict__ h1, const float* __restrict__ W2,
             const float* __restrict__ b2, const float* __restrict__ wbuf,
             float* __restrict__ outv, int cellrow0, int Sps)
{
    __shared__ float As[16][36];
    __shared__ float Bs[16][68];
    const int tid = threadIdx.x;
    const int gl = blockIdx.x;
    const int j0 = blockIdx.y * 64;
    const int r0 = (tid >> 4) * 2;
    const int c0 = (tid & 15) * 4;
    float bload[4];
    #pragma unroll
    for (int j = 0; j < 4; ++j) bload[j] = b2[j0 + c0 + j];
    float accO[2][4] = {};
    const int lrA = tid >> 3;        // 0..31
    const int lkA = (tid & 7) * 2;   // 0..14
    const int lrB = tid >> 2;        // 0..63
    const int lkB = (tid & 3) * 4;
    for (int s = 0; s < Sps; ++s) {
        const float* Ab = h1 + (size_t)(gl * Sps + s) * 32 * DD;
        float accS[2][4] = {};
        for (int k0 = 0; k0 < DD; k0 += 16) {
            float2 a2 = *(const float2*)(Ab + (size_t)lrA * DD + k0 + lkA);
            As[lkA][lrA] = a2.x; As[lkA+1][lrA] = a2.y;
            float4 bv = *(const float4*)(W2 + (size_t)(j0 + lrB) * DD + k0 + lkB);
            Bs[lkB+0][lrB] = bv.x; Bs[lkB+1][lrB] = bv.y; Bs[lkB+2][lrB] = bv.z; Bs[lkB+3][lrB] = bv.w;
            __syncthreads();
            #pragma unroll
            for (int kk = 0; kk < 16; ++kk) {
                float2 a = *(const float2*)&As[kk][r0];
                float4 b = *(const float4*)&Bs[kk][c0];
                float ar[2] = {a.x, a.y};
                float br[4] = {b.x, b.y, b.z, b.w};
                #pragma unroll
                for (int i = 0; i < 2; ++i)
                    #pragma unroll
                    for (int j = 0; j < 4; ++j)
                        accS[i][j] += ar[i] * br[j];
            }
            __syncthreads();
        }
        #pragma unroll
        for (int i = 0; i < 2; ++i) {
            float wt = wbuf[(gl * Sps + s) * 32 + r0 + i];
            #pragma unroll
            for (int j = 0; j < 4; ++j)
                accO[i][j] += wt * fmaxf(accS[i][j] + bload[j], 0.f);
        }
    }
    #pragma unroll
    for (int i = 0; i < 2; ++i)
        #pragma unroll
        for (int j = 0; j < 4; ++j)
            outv[(size_t)(cellrow0 + gl * 32 + r0 + i) * DD + j0 + c0 + j] = accO[i][j];
}

// sc[p,bb] = dot(left, W_bil*right) + child scores ; one wave per (p,bb)
template<bool INSIDE>
__global__ __launch_bounds__(256)
void score_k(const float* __restrict__ iv, const float* __restrict__ ivW,
             const float* __restrict__ ov, const float* __restrict__ isc,
             const float* __restrict__ osc, float* __restrict__ sc,
             int level, int g0, int Pc, int Sps)
{
    int wid = (blockIdx.x * 256 + threadIdx.x) >> 6;
    int lane = threadIdx.x & 63;
    if (wid >= Pc * 32) return;
    int p = wid >> 5, bb = wid & 31;
    int g = g0 + p / Sps, si = p % Sps;
    const float *lp, *rp; float add;
    if (INSIDE) {
        int s = si + 1;
        int lc = ftd(g, g + s), rc = ftd(g + s, g + level);
        lp = iv + (size_t)(lc * 32 + bb) * DD;
        rp = ivW + (size_t)(rc * 32 + bb) * DD;
        add = isc[lc * 32 + bb] + isc[rc * 32 + bb];
    } else {
        int pc, scl;
        if (si < g) { int c = si; pc = ftd(c, g + level); scl = ftd(c, g); }
        else { int c = si + level + 1; pc = ftd(g, c); scl = ftd(g + level, c); }
        lp = ov + (size_t)(pc * 32 + bb) * DD;
        rp = ivW + (size_t)(scl * 32 + bb) * DD;
        add = osc[pc * 32 + bb] + isc[scl * 32 + bb];
    }
    float sum = 0.f;
    #pragma unroll
    for (int i = 0; i < 3; ++i) {
        float4 a = *(const float4*)(lp + i * 256 + lane * 4);
        float4 c = *(const float4*)(rp + i * 256 + lane * 4);
        sum += a.x * c.x + a.y * c.y + a.z * c.z + a.w * c.w;
    }
    #pragma unroll
    for (int off = 32; off; off >>= 1) sum += __shfl_down(sum, off);
    if (lane == 0) sc[p * 32 + bb] = sum + add;
}

// one wave per (gl, bb): softmax over splits, write weights + weighted score
__global__ __launch_bounds__(256)
void softmax_k(const float* __restrict__ sc, float* __restrict__ wbuf,
               float* __restrict__ scout, int cellrow0, int gc, int Sps)
{
    int wid = (blockIdx.x * 256 + threadIdx.x) >> 6;
    int lane = threadIdx.x & 63;
    if (wid >= gc * 32) return;
    int gl = wid >> 5, bb = wid & 31;
    bool act = lane < Sps;
    float x = act ? sc[(gl * Sps + lane) * 32 + bb] : -3.0e38f;
    float m = x;
    #pragma unroll
    for (int off = 32; off; off >>= 1) m = fmaxf(m, __shfl_xor(m, off));
    float e = act ? expf(x - m) : 0.f;
    float ssum = e;
    #pragma unroll
    for (int off = 32; off; off >>= 1) ssum += __shfl_xor(ssum, off);
    float wt = e / ssum;
    if (act) wbuf[(gl * Sps + lane) * 32 + bb] = wt;
    float ws = act ? wt * x : 0.f;
    #pragma unroll
    for (int off = 32; off; off >>= 1) ws += __shfl_xor(ws, off);
    if (lane == 0) scout[cellrow0 + gl * 32 + bb] = ws;
}

__global__ __launch_bounds__(256)
void loss_part(const float* __restrict__ ov, const float* __restrict__ base,
               float* __restrict__ lb)
{
    int wid = (blockIdx.x * 256 + threadIdx.x) >> 6;
    int lane = threadIdx.x & 63;
    if (wid >= NN * 32) return;
    const float* t = ov + (size_t)wid * DD;
    const float* b = base + (size_t)wid * DD;
    float num = 0, nt = 0, nb = 0;
    #pragma unroll
    for (int i = 0; i < 3; ++i) {
        float4 a = *(const float4*)(t + i * 256 + lane * 4);
        float4 c = *(const float4*)(b + i * 256 + lane * 4);
        num += a.x * c.x + a.y * c.y + a.z * c.z + a.w * c.w;
        nt  += a.x * a.x + a.y * a.y + a.z * a.z + a.w * a.w;
        nb  += c.x * c.x + c.y * c.y + c.z * c.z + c.w * c.w;
    }
    #pragma unroll
    for (int off = 32; off; off >>= 1) {
        num += __shfl_down(num, off);
        nt  += __shfl_down(nt, off);
        nb  += __shfl_down(nb, off);
    }
    if (lane == 0) {
        float den = fmaxf(sqrtf(nt) * sqrtf(nb), 1e-8f);
        lb[wid] = 1.f - num / den;
    }
}

__global__ void loss_fin(const float* __restrict__ lb, float* __restrict__ out)
{
    __shared__ float red[256];
    float s = 0;
    for (int i = threadIdx.x; i < NN * 32; i += 256) s += lb[i];
    red[threadIdx.x] = s;
    __syncthreads();
    for (int o = 128; o; o >>= 1) {
        if (threadIdx.x < o) red[threadIdx.x] += red[threadIdx.x + o];
        __syncthreads();
    }
    if (threadIdx.x == 0) out[0] = red[0] / (NN * 32.f);
}

__global__ void init_root(float* __restrict__ ov, const float* __restrict__ rb)
{
    int idx = blockIdx.x * 256 + threadIdx.x;
    if (idx < 32 * DD) ov[(size_t)819 * 32 * DD + idx] = rb[idx % DD];
}

extern "C" void kernel_launch(void* const* d_in, const int* in_sizes, int n_in,
                              void* d_out, int out_size, void* d_ws, size_t ws_size,
                              hipStream_t stream)
{
    const float* base  = (const float*)d_in[0];
    const float* Wbil  = (const float*)d_in[1];
    const float* W1    = (const float*)d_in[2];
    const float* b1    = (const float*)d_in[3];
    const float* W2    = (const float*)d_in[4];
    const float* b2    = (const float*)d_in[5];
    const float* rbias = (const float*)d_in[6];
    float* out = (float*)d_out;

    char* ws = (char*)d_ws;
    const size_t SZV = (size_t)TT * 32 * DD * sizeof(float);
    const size_t SZS = (size_t)TT * 32 * sizeof(float);
    const size_t SZP = (size_t)1560 * 32 * sizeof(float);
    float* iv  = (float*)(ws);
    float* ivW = (float*)(ws + SZV);
    float* ov  = (float*)(ws + 2 * SZV);
    float* isc = (float*)(ws + 3 * SZV);
    float* osc = (float*)(ws + 3 * SZV + SZS);
    float* scb = (float*)(ws + 3 * SZV + 2 * SZS);
    float* wb  = (float*)(ws + 3 * SZV + 2 * SZS + SZP);
    float* lb  = (float*)(ws + 3 * SZV + 2 * SZS + 2 * SZP);
    size_t off_h1 = 3 * SZV + 2 * SZS + 2 * SZP + 8192;
    off_h1 = (off_h1 + 255) & ~(size_t)255;
    float* h1 = (float*)(ws + off_h1);
    size_t avail = (ws_size > off_h1) ? ws_size - off_h1 : 0;

    // --- init ---
    hipMemsetAsync(isc, 0, 2 * SZS, stream);  // isc + osc (adjacent)
    hipMemcpyAsync(iv, base, (size_t)NN * 32 * DD * sizeof(float),
                   hipMemcpyDeviceToDevice, stream);
    init_root<<<(32 * DD + 255) / 256, 256, 0, stream>>>(ov, rbias);
    {   // leaf ivW = W_bil @ iv[:N]
        int M = NN * 32;
        dim3 g((M + 63) / 64, DD / 64);
        gemm_w<MODE_CONTIG, DD, false, false><<<g, 256, 0, stream>>>(
            iv, nullptr, nullptr, Wbil, nullptr, ivW, M, 0, 0, 1);
    }

    // --- inside pass ---
    for (int L = 2; L <= NN; ++L) {
        int S = L - 1, nb = NN + 1 - L;
        int cellbase = TT - (NN - L + 2) * (NN - L + 1) / 2;
        size_t perbegin = (size_t)S * 32 * DD * sizeof(float);
        int GC = (perbegin > 0 && avail >= perbegin) ? (int)(avail / perbegin) : 1;
        if (GC < 1) GC = 1;
        if (GC > nb) GC = nb;
        for (int g0 = 0; g0 < nb; g0 += GC) {
            int gc = (g0 + GC <= nb) ? GC : (nb - g0);
            int Pc = gc * S, Mc = Pc * 32;
            score_k<true><<<(Pc * 32 + 3) / 4, 256, 0, stream>>>(
                iv, ivW, ov, isc, osc, scb, L, g0, Pc, S);
            softmax_k<<<(gc * 32 + 3) / 4, 256, 0, stream>>>(
                scb, wb, isc, (cellbase + g0) * 32, gc, S);
            dim3 g1((Mc + 63) / 64, DD / 64);
            gemm_w<MODE_IN, 2 * DD, true, true><<<g1, 256, 0, stream>>>(
                nullptr, iv, ov, W1, b1, h1, Mc, L, g0, S);
            dim3 g2(gc, DD / 64);
            gemm2_w<<<g2, 256, 0, stream>>>(h1, W2, b2, wb, iv, (cellbase + g0) * 32, S);
        }
        {   // ivW for this level's new cells (contiguous)
            int M = nb * 32;
            dim3 g((M + 63) / 64, DD / 64);
            gemm_w<MODE_CONTIG, DD, false, false><<<g, 256, 0, stream>>>(
                iv + (size_t)cellbase * 32 * DD, nullptr, nullptr, Wbil, nullptr,
                ivW + (size_t)cellbase * 32 * DD, M, 0, 0, 1);
        }
    }

    // --- outside pass ---
    for (int L = NN - 1; L >= 1; --L) {
        int S = NN - L, nb = NN + 1 - L;
        int cellbase = TT - (NN - L + 2) * (NN - L + 1) / 2;
        size_t perbegin = (size_t)S * 32 * DD * sizeof(float);
        int GC = (perbegin > 0 && avail >= perbegin) ? (int)(avail / perbegin) : 1;
        if (GC < 1) GC = 1;
        if (GC > nb) GC = nb;
        for (int g0 = 0; g0 < nb; g0 += GC) {
            int gc = (g0 + GC <= nb) ? GC : (nb - g0);
            int Pc = gc * S, Mc = Pc * 32;
            score_k<false><<<(Pc * 32 + 3) / 4, 256, 0, stream>>>(
                iv, ivW, ov, isc, osc, scb, L, g0, Pc, S);
            softmax_k<<<(gc * 32 + 3) / 4, 256, 0, stream>>>(
                scb, wb, osc, (cellbase + g0) * 32, gc, S);
            dim3 g1((Mc + 63) / 64, DD / 64);
            gemm_w<MODE_OUT, 2 * DD, true, true><<<g1, 256, 0, stream>>>(
                nullptr, iv, ov, W1, b1, h1, Mc, L, g0, S);
            dim3 g2(gc, DD / 64);
            gemm2_w<<<g2, 256, 0, stream>>>(h1, W2, b2, wb, ov, (cellbase + g0) * 32, S);
        }
    }

    // --- loss ---
    hipMemsetAsync(out, 0, sizeof(float), stream);
    loss_part<<<(NN * 32 + 3) / 4, 256, 0, stream>>>(ov, base, lb);
    loss_fin<<<1, 256, 0, stream>>>(lb, out);
}

// Round 2
// 10163.054 us; speedup vs baseline: 16.2654x; 16.2654x over previous
//
#include <hip/hip_runtime.h>
#include <math.h>

#define NN 40
#define DD 768
#define TT 820   // (N+1)*N/2

typedef unsigned short u16;
typedef __attribute__((ext_vector_type(8))) short bfrag8;
typedef __attribute__((ext_vector_type(4))) float facc4;

__device__ __forceinline__ int ftd(int b, int e) {
    int l = e - b;
    return TT - (NN - l + 2) * (NN - l + 1) / 2 + b;
}
__device__ __forceinline__ float bf2f(u16 u) {
    union { unsigned int i; float f; } x; x.i = ((unsigned)u) << 16; return x.f;
}
__device__ __forceinline__ u16 f2bf(float f) {
    unsigned u = __float_as_uint(f);
    u += 0x7fff + ((u >> 16) & 1);
    return (u16)(u >> 16);
}
__device__ __forceinline__ float dot2(unsigned a, unsigned c) {
    return bf2f((u16)a) * bf2f((u16)c) + bf2f((u16)(a >> 16)) * bf2f((u16)(c >> 16));
}

#define GLOAD16(gp, lp) __builtin_amdgcn_global_load_lds( \
    (const __attribute__((address_space(1))) unsigned int*)(gp), \
    (__attribute__((address_space(3))) unsigned int*)(lp), 16, 0, 0)

#define MODE_CONTIG 0
#define MODE_IN 1
#define MODE_OUT 2
// EPI: 0 = plain bf16 store, 1 = relu(+bias) bf16 (h1), 2 = w*relu(+bias) bf16 (v)

// C[m][n] = sum_k A[m][k] * W[n][k]   (A gathered bf16 rows, W row-major [768][KDIM] bf16)
// tile 64(M) x 128(N), BK=32, 4 waves (2x2), each wave 32x64 = 2x4 frags of 16x16x32
template<int MODE, int KDIM, int EPI>
__global__ __launch_bounds__(256)
void mgemm(const u16* __restrict__ Abase,
           const u16* __restrict__ ivb, const u16* __restrict__ ovb,
           const u16* __restrict__ W, const float* __restrict__ bias,
           const float* __restrict__ wbuf, u16* __restrict__ Out,
           int M, int level, int g0, int Sps)
{
    __shared__ __align__(16) u16 As[64 * 32];    // 4 KB
    __shared__ __align__(16) u16 Bs[128 * 32];   // 8 KB
    const int tid = threadIdx.x;
    const int lane = tid & 63;
    const int wv = tid >> 6;
    const int m0 = blockIdx.x * 64;
    const int j0 = blockIdx.y * 128;

    // per-thread A staging source: row m0 + (tid>>2), k-offset (tid&3)*8
    int arow = m0 + (tid >> 2); if (arow >= M) arow = M - 1;
    const int akofs = (tid & 3) * 8;
    const u16 *ap0, *ap1;
    if (MODE == MODE_CONTIG) {
        ap0 = Abase + (size_t)arow * KDIM + akofs;
        ap1 = ap0;
    } else {
        int p = arow >> 5, bb = arow & 31;
        int g = g0 + p / Sps, si = p % Sps;
        if (MODE == MODE_IN) {
            int s = si + 1;
            int lc = ftd(g, g + s), rc = ftd(g + s, g + level);
            ap0 = ivb + (size_t)(lc * 32 + bb) * DD + akofs;
            ap1 = ivb + (size_t)(rc * 32 + bb) * DD + akofs;
        } else {
            int pc, scl;
            if (si < g) { pc = ftd(si, g + level); scl = ftd(si, g); }
            else { int c = si + level + 1; pc = ftd(g, c); scl = ftd(g + level, c); }
            ap0 = ovb + (size_t)(pc * 32 + bb) * DD + akofs;
            ap1 = ivb + (size_t)(scl * 32 + bb) * DD + akofs;
        }
    }
    // B staging: rows j0 + (tid>>2) and +64
    const u16* bp0 = W + (size_t)(j0 + (tid >> 2)) * KDIM + akofs;
    const u16* bp1 = bp0 + (size_t)64 * KDIM;

    u16* AsW = As + wv * 512;   // wave-uniform LDS dest (1 KB per wave)
    u16* BsW = Bs + wv * 512;

    facc4 acc[2][4];
    #pragma unroll
    for (int i = 0; i < 2; ++i)
        #pragma unroll
        for (int j = 0; j < 4; ++j)
            acc[i][j] = (facc4){0.f, 0.f, 0.f, 0.f};

    const int wr = wv >> 1, wc = wv & 1;
    const int fr = lane & 15, fk = (lane >> 4) * 8;

    for (int k0 = 0; k0 < KDIM; k0 += 32) {
        const u16* as;
        if (MODE == MODE_CONTIG) as = ap0 + k0;
        else as = (k0 < DD) ? (ap0 + k0) : (ap1 + (k0 - DD));
        GLOAD16(as, AsW);
        GLOAD16(bp0 + k0, BsW);
        GLOAD16(bp1 + k0, BsW + 2048);
        __syncthreads();

        bfrag8 a[2], b[4];
        #pragma unroll
        for (int fi = 0; fi < 2; ++fi)
            a[fi] = *(const bfrag8*)&As[(wr * 32 + fi * 16 + fr) * 32 + fk];
        #pragma unroll
        for (int fj = 0; fj < 4; ++fj)
            b[fj] = *(const bfrag8*)&Bs[(wc * 64 + fj * 16 + fr) * 32 + fk];
        #pragma unroll
        for (int fi = 0; fi < 2; ++fi)
            #pragma unroll
            for (int fj = 0; fj < 4; ++fj)
                acc[fi][fj] = __builtin_amdgcn_mfma_f32_16x16x32_bf16(
                    a[fi], b[fj], acc[fi][fj], 0, 0, 0);
        __syncthreads();
    }

    const int orow0 = m0 + wr * 32 + (lane >> 4) * 4;
    const int ocol0 = j0 + wc * 64 + (lane & 15);
    #pragma unroll
    for (int fi = 0; fi < 2; ++fi) {
        #pragma unroll
        for (int r = 0; r < 4; ++r) {
            int m = orow0 + fi * 16 + r;
            if (m < M) {
                float wt = (EPI == 2) ? wbuf[m] : 0.f;
                #pragma unroll
                for (int fj = 0; fj < 4; ++fj) {
                    int n = ocol0 + fj * 16;
                    float v = acc[fi][fj][r];
                    if (EPI >= 1) v = fmaxf(v + bias[n], 0.f);
                    if (EPI == 2) v *= wt;
                    Out[(size_t)m * DD + n] = f2bf(v);
                }
            }
        }
    }
}

// reduce over splits: chart[cellrow0 + gl*32+bb][col] = sum_s v[(gl*S+s)*32+bb][col]
__global__ __launch_bounds__(256)
void reduce_k(const u16* __restrict__ v, u16* __restrict__ chart,
              int cellrow0, int gc, int Sps)
{
    int idx = blockIdx.x * 256 + threadIdx.x;
    if (idx >= gc * 32 * DD) return;
    int col = idx % DD, row = idx / DD;       // row = gl*32+bb
    int gl = row >> 5, bb = row & 31;
    float s = 0.f;
    const u16* p = v + ((size_t)(gl * Sps) * 32 + bb) * DD + col;
    for (int si = 0; si < Sps; ++si) s += bf2f(p[(size_t)si * 32 * DD]);
    chart[(size_t)(cellrow0 + row) * DD + col] = f2bf(s);
}

// sc[p,bb] = dot(left, W_bil*right) + child scores ; one wave per (p,bb)
template<bool INSIDE>
__global__ __launch_bounds__(256)
void score_k(const u16* __restrict__ ivb, const u16* __restrict__ ivWb,
             const u16* __restrict__ ovb, const float* __restrict__ isc,
             const float* __restrict__ osc, float* __restrict__ sc,
             int level, int g0, int Pc, int Sps)
{
    int wid = (blockIdx.x * 256 + threadIdx.x) >> 6;
    int lane = threadIdx.x & 63;
    if (wid >= Pc * 32) return;
    int p = wid >> 5, bb = wid & 31;
    int g = g0 + p / Sps, si = p % Sps;
    const u16 *lp, *rp; float add;
    if (INSIDE) {
        int s = si + 1;
        int lc = ftd(g, g + s), rc = ftd(g + s, g + level);
        lp = ivb + (size_t)(lc * 32 + bb) * DD;
        rp = ivWb + (size_t)(rc * 32 + bb) * DD;
        add = isc[lc * 32 + bb] + isc[rc * 32 + bb];
    } else {
        int pc, scl;
        if (si < g) { pc = ftd(si, g + level); scl = ftd(si, g); }
        else { int c = si + level + 1; pc = ftd(g, c); scl = ftd(g + level, c); }
        lp = ovb + (size_t)(pc * 32 + bb) * DD;
        rp = ivWb + (size_t)(scl * 32 + bb) * DD;
        add = osc[pc * 32 + bb] + isc[scl * 32 + bb];
    }
    float sum = 0.f;
    #pragma unroll
    for (int i = 0; i < 3; ++i) {
        uint2 a = *(const uint2*)(lp + i * 256 + lane * 4);
        uint2 c = *(const uint2*)(rp + i * 256 + lane * 4);
        sum += dot2(a.x, c.x) + dot2(a.y, c.y);
    }
    #pragma unroll
    for (int off = 32; off; off >>= 1) sum += __shfl_down(sum, off);
    if (lane == 0) sc[p * 32 + bb] = sum + add;
}

// one wave per (gl, bb): softmax over splits, write weights + weighted score
__global__ __launch_bounds__(256)
void softmax_k(const float* __restrict__ sc, float* __restrict__ wbuf,
               float* __restrict__ scout, int cellrow0, int gc, int Sps)
{
    int wid = (blockIdx.x * 256 + threadIdx.x) >> 6;
    int lane = threadIdx.x & 63;
    if (wid >= gc * 32) return;
    int gl = wid >> 5, bb = wid & 31;
    bool act = lane < Sps;
    float x = act ? sc[(gl * Sps + lane) * 32 + bb] : -3.0e38f;
    float m = x;
    #pragma unroll
    for (int off = 32; off; off >>= 1) m = fmaxf(m, __shfl_xor(m, off));
    float e = act ? expf(x - m) : 0.f;
    float ssum = e;
    #pragma unroll
    for (int off = 32; off; off >>= 1) ssum += __shfl_xor(ssum, off);
    float wt = e / ssum;
    if (act) wbuf[(gl * Sps + lane) * 32 + bb] = wt;
    float ws = act ? wt * x : 0.f;
    #pragma unroll
    for (int off = 32; off; off >>= 1) ws += __shfl_xor(ws, off);
    if (lane == 0) scout[cellrow0 + gl * 32 + bb] = ws;
}

__global__ __launch_bounds__(256)
void loss_part(const u16* __restrict__ ovb, const float* __restrict__ base,
               float* __restrict__ lb)
{
    int wid = (blockIdx.x * 256 + threadIdx.x) >> 6;
    int lane = threadIdx.x & 63;
    if (wid >= NN * 32) return;
    const u16* t = ovb + (size_t)wid * DD;
    const float* b = base + (size_t)wid * DD;
    float num = 0, nt = 0, nb = 0;
    #pragma unroll
    for (int i = 0; i < 3; ++i) {
        uint2 a2 = *(const uint2*)(t + i * 256 + lane * 4);
        float4 c = *(const float4*)(b + i * 256 + lane * 4);
        float a0 = bf2f((u16)a2.x), a1 = bf2f((u16)(a2.x >> 16));
        float a2f = bf2f((u16)a2.y), a3 = bf2f((u16)(a2.y >> 16));
        num += a0 * c.x + a1 * c.y + a2f * c.z + a3 * c.w;
        nt  += a0 * a0 + a1 * a1 + a2f * a2f + a3 * a3;
        nb  += c.x * c.x + c.y * c.y + c.z * c.z + c.w * c.w;
    }
    #pragma unroll
    for (int off = 32; off; off >>= 1) {
        num += __shfl_down(num, off);
        nt  += __shfl_down(nt, off);
        nb  += __shfl_down(nb, off);
    }
    if (lane == 0) {
        float den = fmaxf(sqrtf(nt) * sqrtf(nb), 1e-8f);
        lb[wid] = 1.f - num / den;
    }
}

__global__ void loss_fin(const float* __restrict__ lb, float* __restrict__ out)
{
    __shared__ float red[256];
    float s = 0;
    for (int i = threadIdx.x; i < NN * 32; i += 256) s += lb[i];
    red[threadIdx.x] = s;
    __syncthreads();
    for (int o = 128; o; o >>= 1) {
        if (threadIdx.x < o) red[threadIdx.x] += red[threadIdx.x + o];
        __syncthreads();
    }
    if (threadIdx.x == 0) out[0] = red[0] / (NN * 32.f);
}

__global__ void cvt_k(const float* __restrict__ in, u16* __restrict__ out, int n)
{
    int idx = blockIdx.x * 256 + threadIdx.x;
    if (idx < n) out[idx] = f2bf(in[idx]);
}

__global__ void init_rootb(u16* __restrict__ ovb, const float* __restrict__ rb)
{
    int idx = blockIdx.x * 256 + threadIdx.x;
    if (idx < 32 * DD) ovb[(size_t)819 * 32 * DD + idx] = f2bf(rb[idx % DD]);
}

extern "C" void kernel_launch(void* const* d_in, const int* in_sizes, int n_in,
                              void* d_out, int out_size, void* d_ws, size_t ws_size,
                              hipStream_t stream)
{
    const float* base  = (const float*)d_in[0];
    const float* Wbil  = (const float*)d_in[1];
    const float* W1    = (const float*)d_in[2];
    const float* b1    = (const float*)d_in[3];
    const float* W2    = (const float*)d_in[4];
    const float* b2    = (const float*)d_in[5];
    const float* rbias = (const float*)d_in[6];
    float* out = (float*)d_out;

    char* ws = (char*)d_ws;
    size_t off = 0;
    auto alloc = [&](size_t bytes) { size_t o = off; off = (off + bytes + 255) & ~(size_t)255; return o; };
    const size_t SB = (size_t)TT * 32 * DD * 2;          // bf16 chart
    u16*  ivb  = (u16*)(ws + alloc(SB));
    u16*  ivWb = (u16*)(ws + alloc(SB));
    u16*  ovb  = (u16*)(ws + alloc(SB));
    u16*  W1b  = (u16*)(ws + alloc((size_t)DD * 2 * DD * 2));
    u16*  W2b  = (u16*)(ws + alloc((size_t)DD * DD * 2));
    u16*  Wbb  = (u16*)(ws + alloc((size_t)DD * DD * 2));
    float* isc = (float*)(ws + alloc((size_t)TT * 32 * 4));
    float* osc = (float*)(ws + alloc((size_t)TT * 32 * 4));
    float* scb = (float*)(ws + alloc((size_t)1560 * 32 * 4));
    float* wb  = (float*)(ws + alloc((size_t)1560 * 32 * 4));
    float* lb  = (float*)(ws + alloc((size_t)NN * 32 * 4));
    size_t remaining = (ws_size > off) ? (ws_size - off) : 0;
    size_t half = (remaining / 2) & ~(size_t)255;
    u16* h1b = (u16*)(ws + off);
    u16* vb  = (u16*)(ws + off + half);

    // --- init: converts + zeros ---
    hipMemsetAsync(isc, 0, (size_t)TT * 32 * 4 * 2 + 512, stream); // isc+osc (adjacent, padded)
    cvt_k<<<(DD * 2 * DD + 255) / 256, 256, 0, stream>>>(W1, W1b, DD * 2 * DD);
    cvt_k<<<(DD * DD + 255) / 256, 256, 0, stream>>>(W2, W2b, DD * DD);
    cvt_k<<<(DD * DD + 255) / 256, 256, 0, stream>>>(Wbil, Wbb, DD * DD);
    cvt_k<<<(NN * 32 * DD + 255) / 256, 256, 0, stream>>>(base, ivb, NN * 32 * DD);
    init_rootb<<<(32 * DD + 255) / 256, 256, 0, stream>>>(ovb, rbias);
    {   // leaf ivW
        int M = NN * 32;
        dim3 g((M + 63) / 64, DD / 128);
        mgemm<MODE_CONTIG, DD, 0><<<g, 256, 0, stream>>>(
            ivb, nullptr, nullptr, Wbb, nullptr, nullptr, ivWb, M, 0, 0, 1);
    }

    // --- inside pass ---
    for (int L = 2; L <= NN; ++L) {
        int S = L - 1, nb = NN + 1 - L;
        int cellbase = TT - (NN - L + 2) * (NN - L + 1) / 2;
        size_t perone = (size_t)S * 32 * DD * 2;
        int GC = (half >= perone) ? (int)(half / perone) : 1;
        if (GC < 1) GC = 1;
        if (GC > nb) GC = nb;
        for (int g0 = 0; g0 < nb; g0 += GC) {
            int gc = (g0 + GC <= nb) ? GC : (nb - g0);
            int Pc = gc * S, Mc = Pc * 32;
            score_k<true><<<(Pc * 32 + 3) / 4, 256, 0, stream>>>(
                ivb, ivWb, ovb, isc, osc, scb, L, g0, Pc, S);
            softmax_k<<<(gc * 32 + 3) / 4, 256, 0, stream>>>(
                scb, wb, isc, (cellbase + g0) * 32, gc, S);
            dim3 g1((Mc + 63) / 64, DD / 128);
            mgemm<MODE_IN, 2 * DD, 1><<<g1, 256, 0, stream>>>(
                nullptr, ivb, ovb, W1b, b1, nullptr, h1b, Mc, L, g0, S);
            mgemm<MODE_CONTIG, DD, 2><<<g1, 256, 0, stream>>>(
                h1b, nullptr, nullptr, W2b, b2, wb, vb, Mc, 0, 0, 1);
            reduce_k<<<(gc * 32 * DD + 255) / 256, 256, 0, stream>>>(
                vb, ivb, (cellbase + g0) * 32, gc, S);
        }
        {   // ivW for new cells
            int M = nb * 32;
            dim3 g((M + 63) / 64, DD / 128);
            mgemm<MODE_CONTIG, DD, 0><<<g, 256, 0, stream>>>(
                ivb + (size_t)cellbase * 32 * DD, nullptr, nullptr, Wbb, nullptr,
                nullptr, ivWb + (size_t)cellbase * 32 * DD, M, 0, 0, 1);
        }
    }

    // --- outside pass ---
    for (int L = NN - 1; L >= 1; --L) {
        int S = NN - L, nb = NN + 1 - L;
        int cellbase = TT - (NN - L + 2) * (NN - L + 1) / 2;
        size_t perone = (size_t)S * 32 * DD * 2;
        int GC = (half >= perone) ? (int)(half / perone) : 1;
        if (GC < 1) GC = 1;
        if (GC > nb) GC = nb;
        for (int g0 = 0; g0 < nb; g0 += GC) {
            int gc = (g0 + GC <= nb) ? GC : (nb - g0);
            int Pc = gc * S, Mc = Pc * 32;
            score_k<false><<<(Pc * 32 + 3) / 4, 256, 0, stream>>>(
                ivb, ivWb, ovb, isc, osc, scb, L, g0, Pc, S);
            softmax_k<<<(gc * 32 + 3) / 4, 256, 0, stream>>>(
                scb, wb, osc, (cellbase + g0) * 32, gc, S);
            dim3 g1((Mc + 63) / 64, DD / 128);
            mgemm<MODE_OUT, 2 * DD, 1><<<g1, 256, 0, stream>>>(
                nullptr, ivb, ovb, W1b, b1, nullptr, h1b, Mc, L, g0, S);
            mgemm<MODE_CONTIG, DD, 2><<<g1, 256, 0, stream>>>(
                h1b, nullptr, nullptr, W2b, b2, wb, vb, Mc, 0, 0, 1);
            reduce_k<<<(gc * 32 * DD + 255) / 256, 256, 0, stream>>>(
                vb, ovb, (cellbase + g0) * 32, gc, S);
        }
    }

    // --- loss ---
    loss_part<<<(NN * 32 + 3) / 4, 256, 0, stream>>>(ovb, base, lb);
    loss_fin<<<1, 256, 0, stream>>>(lb, out);
}